// Round 1
// baseline (602.824 us; speedup 1.0000x reference)
//
#include <hip/hip_runtime.h>
#include <hip/hip_bf16.h>

#define H    112
#define W    112
#define HW   12544
#define CIN  64
#define COUT 128
#define BATCH 8
#define KK   9
#define OFFC 18
#define EPS  1e-5f
#define TP   32   // pixels per deform block

// ---------------- K1: offset conv (3x3, pad 1, 18 out channels) ----------------
// block = one output row (128 threads, 112 active), grid = (H, B).
// Each thread computes all 18 output channels for one pixel; weights are
// wave-uniform -> scalar loads.
__global__ __launch_bounds__(128) void k_offset_conv(
    const float* __restrict__ x, const float* __restrict__ w,
    const float* __restrict__ bias, float* __restrict__ out) {
  int b = blockIdx.y;
  int ho = blockIdx.x;
  int wo = threadIdx.x;
  bool active = wo < W;
  const float* xb = x + (size_t)b * CIN * HW;
  float acc[OFFC];
#pragma unroll
  for (int oc = 0; oc < OFFC; ++oc) acc[oc] = bias[oc];
  for (int ci = 0; ci < CIN; ++ci) {
    const float* xp = xb + ci * HW;
#pragma unroll
    for (int kh = 0; kh < 3; ++kh) {
      int hy = ho + kh - 1;
      if (hy < 0 || hy >= H) continue;   // wave-uniform
      const float* row = xp + hy * W;
#pragma unroll
      for (int kw = 0; kw < 3; ++kw) {
        int wx = wo + kw - 1;
        float xv = (active && wx >= 0 && wx < W) ? row[wx] : 0.f;
        int widx = ci * 9 + kh * 3 + kw;
#pragma unroll
        for (int oc = 0; oc < OFFC; ++oc)
          acc[oc] = fmaf(xv, w[oc * 576 + widx], acc[oc]);
      }
    }
  }
  if (active) {
    int p = ho * W + wo;
#pragma unroll
    for (int oc = 0; oc < OFFC; ++oc)
      out[((size_t)b * OFFC + oc) * HW + p] = acc[oc];
  }
}

// ---------------- K2: transpose w_dcn [128][576] -> wT [576][128] ----------------
__global__ void k_transpose_w(const float* __restrict__ w, float* __restrict__ wT) {
  int i = blockIdx.x * 256 + threadIdx.x;
  if (i >= COUT * 576) return;
  int co = i / 576, k = i - co * 576;
  wT[k * COUT + co] = w[i];
}

// ---------------- K3: deformable conv -> y [8][128][112][112] ----------------
// Block: 128 threads, tile = 32 pixels x 128 output channels.
// Phase A: bilinear meta (4 clamped indices + 4 validity-folded weights) per (tap, px).
// Phase B (x4 ci-chunks of 16): stage samp[144][32] in LDS, then register-tiled
// GEMM: each thread owns 8 co x 4 px accumulators; per k: 1 ds_read_b128 (samp)
// + 2 global float4 (weights, L2-hot) + 32 v_fmac.
__global__ __launch_bounds__(128) void k_deform(
    const float* __restrict__ x, const float* __restrict__ off,
    const float* __restrict__ wT, float* __restrict__ y) {
  __shared__ __align__(16) float s_w[KK][TP][4];
  __shared__ __align__(16) int   s_i[KK][TP][4];
  __shared__ __align__(16) float s_samp[144][TP];

  int b = blockIdx.y;
  int p0 = blockIdx.x * TP;
  int tid = threadIdx.x;

  // ---- Phase A: bilinear metadata ----
  for (int it = tid; it < KK * TP; it += 128) {
    int kk = it >> 5;       // KK*TP = 288, exact
    int px = it & 31;
    int p = p0 + px;
    int ho = p / W, wo = p - ho * W;
    float dy = off[((size_t)b * OFFC + 2 * kk) * HW + p];
    float dx = off[((size_t)b * OFFC + 2 * kk + 1) * HW + p];
    float py = dy + (float)(ho - 1 + kk / 3);
    float pxx = dx + (float)(wo - 1 + kk % 3);
    float y0f = floorf(py), x0f = floorf(pxx);
    float wy1 = py - y0f, wx1 = pxx - x0f;
    int y0 = (int)y0f, x0 = (int)x0f;
    int y1 = y0 + 1, x1 = x0 + 1;
    float vy0 = (y0 >= 0 && y0 < H) ? 1.f : 0.f;
    float vy1 = (y1 >= 0 && y1 < H) ? 1.f : 0.f;
    float vx0 = (x0 >= 0 && x0 < W) ? 1.f : 0.f;
    float vx1 = (x1 >= 0 && x1 < W) ? 1.f : 0.f;
    int cy0 = min(max(y0, 0), H - 1), cy1 = min(max(y1, 0), H - 1);
    int cx0 = min(max(x0, 0), W - 1), cx1 = min(max(x1, 0), W - 1);
    s_w[kk][px][0] = (1.f - wy1) * (1.f - wx1) * vy0 * vx0;
    s_w[kk][px][1] = (1.f - wy1) * wx1 * vy0 * vx1;
    s_w[kk][px][2] = wy1 * (1.f - wx1) * vy1 * vx0;
    s_w[kk][px][3] = wy1 * wx1 * vy1 * vx1;
    s_i[kk][px][0] = cy0 * W + cx0;
    s_i[kk][px][1] = cy0 * W + cx1;
    s_i[kk][px][2] = cy1 * W + cx0;
    s_i[kk][px][3] = cy1 * W + cx1;
  }

  int pxg = tid & 7;          // 8 groups of 4 consecutive pixels
  int cog = tid >> 3;         // 16 groups of 8 consecutive channels
  float acc[8][4];
#pragma unroll
  for (int i = 0; i < 8; ++i)
#pragma unroll
    for (int j = 0; j < 4; ++j) acc[i][j] = 0.f;

  const float* xb = x + (size_t)b * CIN * HW;

  for (int ci0 = 0; ci0 < CIN; ci0 += 16) {
    __syncthreads();
    // ---- stage samples: 144 k-rows x 32 px ----
    for (int it = tid; it < 144 * TP; it += 128) {   // 36 iters, exact
      int ck = it >> 5;
      int px = it & 31;
      int cil = ck / 9, kk = ck - cil * 9;
      const float* xp = xb + (ci0 + cil) * HW;
      float4 wv = *(const float4*)&s_w[kk][px][0];
      int4  iv = *(const int4*)&s_i[kk][px][0];
      float v = wv.x * xp[iv.x] + wv.y * xp[iv.y] + wv.z * xp[iv.z] + wv.w * xp[iv.w];
      s_samp[ck][px] = v;
    }
    __syncthreads();
    // ---- register-tiled GEMM over this chunk ----
    const float* wrow = wT + (size_t)(ci0 * 9) * COUT + cog * 8;
#pragma unroll 4
    for (int ck = 0; ck < 144; ++ck) {
      float4 s = *(const float4*)&s_samp[ck][pxg * 4];
      float4 wA = *(const float4*)&wrow[ck * COUT];
      float4 wB = *(const float4*)&wrow[ck * COUT + 4];
#define FMA_ROW(i, wv)                                \
      acc[i][0] = fmaf(wv, s.x, acc[i][0]);           \
      acc[i][1] = fmaf(wv, s.y, acc[i][1]);           \
      acc[i][2] = fmaf(wv, s.z, acc[i][2]);           \
      acc[i][3] = fmaf(wv, s.w, acc[i][3]);
      FMA_ROW(0, wA.x) FMA_ROW(1, wA.y) FMA_ROW(2, wA.z) FMA_ROW(3, wA.w)
      FMA_ROW(4, wB.x) FMA_ROW(5, wB.y) FMA_ROW(6, wB.z) FMA_ROW(7, wB.w)
#undef FMA_ROW
    }
  }

  // ---- store y (b_dcn omitted: it cancels exactly through batch-norm) ----
#pragma unroll
  for (int i = 0; i < 8; ++i) {
    int co = cog * 8 + i;
    float4 v = make_float4(acc[i][0], acc[i][1], acc[i][2], acc[i][3]);
    *(float4*)&y[((size_t)b * COUT + co) * HW + p0 + pxg * 4] = v;
  }
}

// ---------------- K4: per-channel batch stats ----------------
__global__ __launch_bounds__(256) void k_stats(const float* __restrict__ y,
                                               float* __restrict__ stats) {
  int c = blockIdx.x;
  int tid = threadIdx.x;
  float s = 0.f, s2 = 0.f;
  for (int b = 0; b < BATCH; ++b) {
    const float4* yp = (const float4*)(y + ((size_t)b * COUT + c) * HW);
    for (int p = tid; p < HW / 4; p += 256) {
      float4 v = yp[p];
      s += v.x + v.y + v.z + v.w;
      s2 += v.x * v.x + v.y * v.y + v.z * v.z + v.w * v.w;
    }
  }
#pragma unroll
  for (int o = 32; o > 0; o >>= 1) {
    s += __shfl_down(s, o, 64);
    s2 += __shfl_down(s2, o, 64);
  }
  __shared__ float ls[4], ls2[4];
  int lane = tid & 63, wid = tid >> 6;
  if (lane == 0) { ls[wid] = s; ls2[wid] = s2; }
  __syncthreads();
  if (tid == 0) {
    float S = ls[0] + ls[1] + ls[2] + ls[3];
    float S2 = ls2[0] + ls2[1] + ls2[2] + ls2[3];
    const float N = (float)(BATCH * HW);
    float mean = S / N;
    float var = S2 / N - mean * mean;
    stats[c] = mean;
    stats[COUT + c] = rsqrtf(var + EPS);
  }
}

// ---------------- K5: normalize + scale/shift + ReLU ----------------
__global__ __launch_bounds__(256) void k_norm(const float* __restrict__ y,
                                              const float* __restrict__ stats,
                                              const float* __restrict__ gamma,
                                              const float* __restrict__ beta,
                                              float* __restrict__ out) {
  int i4 = blockIdx.x * 256 + threadIdx.x;
  const int total4 = BATCH * COUT * HW / 4;
  if (i4 >= total4) return;
  size_t i = (size_t)i4 * 4;
  int c = (int)((i / HW) & (COUT - 1));
  float m = stats[c], r = stats[COUT + c];
  float g = gamma[c], bt = beta[c];
  float4 v = *(const float4*)&y[i];
  v.x = fmaxf(0.f, (v.x - m) * r * g + bt);
  v.y = fmaxf(0.f, (v.y - m) * r * g + bt);
  v.z = fmaxf(0.f, (v.z - m) * r * g + bt);
  v.w = fmaxf(0.f, (v.w - m) * r * g + bt);
  *(float4*)&out[i] = v;
}

extern "C" void kernel_launch(void* const* d_in, const int* in_sizes, int n_in,
                              void* d_out, int out_size, void* d_ws, size_t ws_size,
                              hipStream_t stream) {
  const float* x     = (const float*)d_in[0];
  const float* w_off = (const float*)d_in[1];
  const float* b_off = (const float*)d_in[2];
  const float* w_dcn = (const float*)d_in[3];
  // d_in[4] = b_dcn: cancels exactly through batch-norm (per-channel mean shift)
  const float* gamma = (const float*)d_in[5];
  const float* beta  = (const float*)d_in[6];
  float* out = (float*)d_out;

  float* ws = (float*)d_ws;
  float* off_buf = ws;                          // 1,806,336 floats
  float* wT      = off_buf + 1806336;           //    73,728 floats
  float* y       = wT + 73728;                  // 12,845,056 floats
  float* stats   = y + 12845056;                //       256 floats
  // total ~58.9 MB of workspace

  k_offset_conv<<<dim3(H, BATCH), 128, 0, stream>>>(x, w_off, b_off, off_buf);
  k_transpose_w<<<(COUT * 576 + 255) / 256, 256, 0, stream>>>(w_dcn, wT);
  k_deform<<<dim3(HW / TP, BATCH), 128, 0, stream>>>(x, off_buf, wT, y);
  k_stats<<<COUT, 256, 0, stream>>>(y, stats);
  k_norm<<<(BATCH * COUT * HW / 4 + 255) / 256, 256, 0, stream>>>(y, stats, gamma, beta, out);
}

// Round 2
// 269.454 us; speedup vs baseline: 2.2372x; 2.2372x over previous
//
#include <hip/hip_runtime.h>

#define H    112
#define W    112
#define HW   12544
#define CIN  64
#define COUT 128
#define BATCH 8
#define KK   9
#define OFFC 18
#define EPS  1e-5f
#define TP   32      // pixels per deform block
#define KDIM 576     // CIN*KK
#define KPAD 584     // samp row padding: 16B lane stride = 4 words mod 32 -> conflict-free

typedef unsigned short ushort;
typedef unsigned int uint;
typedef __attribute__((ext_vector_type(8))) short short8;
typedef __attribute__((ext_vector_type(8))) ushort ushort8;
typedef __attribute__((ext_vector_type(4))) float floatx4;

__device__ __forceinline__ ushort f2bf(float f) {
  uint u = __float_as_uint(f);
  u = (u + 0x7FFFu + ((u >> 16) & 1u)) >> 16;   // RNE
  return (ushort)u;
}

// ---------------- K0: transpose x [B][CIN][HW] -> xT [B][HW][CIN] ----------------
__global__ __launch_bounds__(256) void k_transpose_x(
    const float* __restrict__ x, float* __restrict__ xT) {
  __shared__ float tile[64][65];
  int b = blockIdx.y;
  int p0 = blockIdx.x * 64;
  int tid = threadIdx.x;
  int j = tid & 63, cb = tid >> 6;
#pragma unroll
  for (int i = 0; i < 16; ++i) {
    int ci = cb * 16 + i;
    tile[ci][j] = x[((size_t)(b * CIN + ci)) * HW + p0 + j];
  }
  __syncthreads();
  int ci2 = tid & 63;
#pragma unroll
  for (int i = 0; i < 16; ++i) {
    int p = cb * 16 + i;
    xT[((size_t)b * HW + p0 + p) * 64 + ci2] = tile[ci2][p];
  }
}

// ---------------- K2: weight reorders ----------------
// w_r[(kk*64+ci)*18+oc] = w_off[oc][ci][kk]   (fp32, for offset conv)
// w_mf[co*576 + kk*64 + ci] = bf16(w_dcn[co][ci][kk])   (for MFMA)
__global__ __launch_bounds__(256) void k_prep_w(
    const float* __restrict__ w_off, const float* __restrict__ w_dcn,
    float* __restrict__ w_r, ushort* __restrict__ w_mf) {
  int i = blockIdx.x * 256 + threadIdx.x;
  if (i < OFFC * KDIM) {
    int oc = i / KDIM, rem = i - oc * KDIM;
    int ci = rem / KK, kk = rem - ci * KK;
    w_r[(kk * 64 + ci) * OFFC + oc] = w_off[i];
  } else if (i < OFFC * KDIM + COUT * KDIM) {
    int jj = i - OFFC * KDIM;
    int co = jj / KDIM, rem = jj - co * KDIM;
    int ci = rem / KK, kk = rem - ci * KK;
    w_mf[co * KDIM + kk * 64 + ci] = f2bf(w_dcn[jj]);
  }
}

// ---------------- K1: offset conv on xT ----------------
// 1 thread/pixel; grid (49, B). Per tap: 16 float4 channel loads + 64*18 FMA
// with wave-uniform weights (scalar loads from w_r).
__global__ __launch_bounds__(256) void k_offset_conv(
    const float* __restrict__ xT, const float* __restrict__ w_r,
    const float* __restrict__ bias, float* __restrict__ out) {
  int b = blockIdx.y;
  int p = blockIdx.x * 256 + threadIdx.x;   // 49*256 == HW exactly
  int ho = p / W, wo = p - ho * W;
  float acc[OFFC];
#pragma unroll
  for (int oc = 0; oc < OFFC; ++oc) acc[oc] = bias[oc];
  const float* xb = xT + (size_t)b * HW * 64;
  for (int t = 0; t < 9; ++t) {
    int yy = ho + t / 3 - 1;
    int xx = wo + t % 3 - 1;
    bool valid = (yy >= 0) & (yy < H) & (xx >= 0) & (xx < W);
    const float4* src = (const float4*)(xb + ((size_t)(yy * W + xx) << 6));
    const float* wbase = w_r + t * 64 * OFFC;
    if (valid) {
#pragma unroll 2
      for (int cig = 0; cig < 16; ++cig) {
        float4 v = src[cig];
#pragma unroll
        for (int jj = 0; jj < 4; ++jj) {
          float xv = (jj == 0) ? v.x : (jj == 1) ? v.y : (jj == 2) ? v.z : v.w;
          const float* wp = wbase + (cig * 4 + jj) * OFFC;
#pragma unroll
          for (int oc = 0; oc < OFFC; ++oc)
            acc[oc] = fmaf(xv, wp[oc], acc[oc]);
        }
      }
    }
  }
#pragma unroll
  for (int oc = 0; oc < OFFC; ++oc)
    out[((size_t)b * OFFC + oc) * HW + p] = acc[oc];
}

// ---------------- K3: deformable conv via bf16 MFMA -> y [B][COUT][HW] ----------------
// 256 threads (4 waves), tile 32 px x 128 co.
// Phase A: bilinear meta. Phase B: sample full K=576 into LDS bf16 (float4
// corner reads from xT). Phase C: 16x16x32 bf16 MFMA, A = w_mf (L2-hot
// global), B = samp (LDS). K order: k = kk*64 + ci (matches w_mf).
__global__ __launch_bounds__(256) void k_deform(
    const float* __restrict__ xT, const float* __restrict__ off,
    const ushort* __restrict__ w_mf, float* __restrict__ y) {
  __shared__ float4 s_w[KK][TP];
  __shared__ int4   s_i[KK][TP];
  __shared__ ushort samp[TP][KPAD];

  int b = blockIdx.y;
  int p0 = blockIdx.x * TP;
  int tid = threadIdx.x;
  const float* xb = xT + (size_t)b * HW * 64;

  // ---- Phase A: bilinear metadata (288 tasks) ----
  for (int it = tid; it < KK * TP; it += 256) {
    int kk = it >> 5;
    int px = it & 31;
    int p = p0 + px;
    int ho = p / W, wo = p - ho * W;
    float dy = off[((size_t)b * OFFC + 2 * kk) * HW + p];
    float dx = off[((size_t)b * OFFC + 2 * kk + 1) * HW + p];
    float py = dy + (float)(ho - 1 + kk / 3);
    float pxx = dx + (float)(wo - 1 + kk % 3);
    float y0f = floorf(py), x0f = floorf(pxx);
    float wy1 = py - y0f, wx1 = pxx - x0f;
    int y0 = (int)y0f, x0 = (int)x0f;
    int y1 = y0 + 1, x1 = x0 + 1;
    float vy0 = (y0 >= 0 && y0 < H) ? 1.f : 0.f;
    float vy1 = (y1 >= 0 && y1 < H) ? 1.f : 0.f;
    float vx0 = (x0 >= 0 && x0 < W) ? 1.f : 0.f;
    float vx1 = (x1 >= 0 && x1 < W) ? 1.f : 0.f;
    int cy0 = min(max(y0, 0), H - 1), cy1 = min(max(y1, 0), H - 1);
    int cx0 = min(max(x0, 0), W - 1), cx1 = min(max(x1, 0), W - 1);
    s_w[kk][px] = make_float4((1.f - wy1) * (1.f - wx1) * vy0 * vx0,
                              (1.f - wy1) * wx1 * vy0 * vx1,
                              wy1 * (1.f - wx1) * vy1 * vx0,
                              wy1 * wx1 * vy1 * vx1);
    s_i[kk][px] = make_int4((cy0 * W + cx0) << 6, (cy0 * W + cx1) << 6,
                            (cy1 * W + cx0) << 6, (cy1 * W + cx1) << 6);
  }
  __syncthreads();

  // ---- Phase B: sampling. 2304 tasks = 32px x 9kk x 8cig (8 ci each) ----
#pragma unroll
  for (int r = 0; r < 9; ++r) {
    int it = tid + r * 256;
    int px = it / 72;
    int rem = it - px * 72;
    int kk = rem >> 3;
    int cig = rem & 7;
    int ci0 = cig * 8;
    float4 wv = s_w[kk][px];
    int4 iv = s_i[kk][px];
    const float4* c0 = (const float4*)(xb + iv.x + ci0);
    const float4* c1 = (const float4*)(xb + iv.y + ci0);
    const float4* c2 = (const float4*)(xb + iv.z + ci0);
    const float4* c3 = (const float4*)(xb + iv.w + ci0);
    float4 a0 = c0[0], a1 = c0[1];
    float4 b0 = c1[0], b1 = c1[1];
    float4 d0 = c2[0], d1 = c2[1];
    float4 e0 = c3[0], e1 = c3[1];
    float r0x = wv.x * a0.x + wv.y * b0.x + wv.z * d0.x + wv.w * e0.x;
    float r0y = wv.x * a0.y + wv.y * b0.y + wv.z * d0.y + wv.w * e0.y;
    float r0z = wv.x * a0.z + wv.y * b0.z + wv.z * d0.z + wv.w * e0.z;
    float r0w = wv.x * a0.w + wv.y * b0.w + wv.z * d0.w + wv.w * e0.w;
    float r1x = wv.x * a1.x + wv.y * b1.x + wv.z * d1.x + wv.w * e1.x;
    float r1y = wv.x * a1.y + wv.y * b1.y + wv.z * d1.y + wv.w * e1.y;
    float r1z = wv.x * a1.z + wv.y * b1.z + wv.z * d1.z + wv.w * e1.z;
    float r1w = wv.x * a1.w + wv.y * b1.w + wv.z * d1.w + wv.w * e1.w;
    ushort8 pk;
    pk[0] = f2bf(r0x); pk[1] = f2bf(r0y); pk[2] = f2bf(r0z); pk[3] = f2bf(r0w);
    pk[4] = f2bf(r1x); pk[5] = f2bf(r1y); pk[6] = f2bf(r1z); pk[7] = f2bf(r1w);
    *(ushort8*)&samp[px][kk * 64 + ci0] = pk;
  }
  __syncthreads();

  // ---- Phase C: MFMA GEMM. wave w: co block 32w..32w+31; 2 M-tiles x 2 N-tiles ----
  int wave = tid >> 6, lane = tid & 63;
  int row16 = lane & 15, quad = lane >> 4;
  int koff = quad * 8;
  int co_base = wave * 32;
  const short8* wa0 = (const short8*)(w_mf + (size_t)(co_base + row16) * KDIM + koff);
  const short8* wa1 = (const short8*)(w_mf + (size_t)(co_base + 16 + row16) * KDIM + koff);
  const short8* sb0 = (const short8*)&samp[row16][koff];
  const short8* sb1 = (const short8*)&samp[16 + row16][koff];

  floatx4 acc00 = {0.f, 0.f, 0.f, 0.f}, acc01 = acc00, acc10 = acc00, acc11 = acc00;
#pragma unroll
  for (int ks = 0; ks < KDIM / 32; ++ks) {
    short8 A0 = wa0[ks * 4];          // stride 32 elems = 4 short8
    short8 A1 = wa1[ks * 4];
    short8 B0 = sb0[ks * 4 + 0 * 0];  // LDS row stride handled below
    short8 B1 = sb1[ks * 4];
    B0 = *(const short8*)((const ushort*)&samp[row16][koff] + ks * 32);
    B1 = *(const short8*)((const ushort*)&samp[16 + row16][koff] + ks * 32);
    acc00 = __builtin_amdgcn_mfma_f32_16x16x32_bf16(A0, B0, acc00, 0, 0, 0);
    acc01 = __builtin_amdgcn_mfma_f32_16x16x32_bf16(A0, B1, acc01, 0, 0, 0);
    acc10 = __builtin_amdgcn_mfma_f32_16x16x32_bf16(A1, B0, acc10, 0, 0, 0);
    acc11 = __builtin_amdgcn_mfma_f32_16x16x32_bf16(A1, B1, acc11, 0, 0, 0);
  }

  // ---- epilogue: C/D layout col=lane&15 (px), row=quad*4+reg (co) ----
  float* yb = y + (size_t)b * COUT * HW + p0;
#pragma unroll
  for (int reg = 0; reg < 4; ++reg) {
    int r0 = quad * 4 + reg;
    yb[(size_t)(co_base + r0) * HW + row16]      = acc00[reg];
    yb[(size_t)(co_base + r0) * HW + 16 + row16] = acc01[reg];
    yb[(size_t)(co_base + 16 + r0) * HW + row16]      = acc10[reg];
    yb[(size_t)(co_base + 16 + r0) * HW + 16 + row16] = acc11[reg];
  }
}

// ---------------- K4: per-channel partial stats (512 blocks, atomics) ----------------
__global__ __launch_bounds__(256) void k_stats(const float* __restrict__ y,
                                               float* __restrict__ stats) {
  int c = blockIdx.x & 127;
  int half = blockIdx.x >> 7;     // 0..3, 2 batches each
  int tid = threadIdx.x;
  float s = 0.f, s2 = 0.f;
#pragma unroll
  for (int bb = 0; bb < 2; ++bb) {
    int b = half * 2 + bb;
    const float4* yp = (const float4*)(y + ((size_t)b * COUT + c) * HW);
    for (int p = tid; p < HW / 4; p += 256) {
      float4 v = yp[p];
      s += v.x + v.y + v.z + v.w;
      s2 += v.x * v.x + v.y * v.y + v.z * v.z + v.w * v.w;
    }
  }
#pragma unroll
  for (int o = 32; o > 0; o >>= 1) {
    s += __shfl_down(s, o, 64);
    s2 += __shfl_down(s2, o, 64);
  }
  __shared__ float ls[4], ls2[4];
  int lane = tid & 63, wid = tid >> 6;
  if (lane == 0) { ls[wid] = s; ls2[wid] = s2; }
  __syncthreads();
  if (tid == 0) {
    atomicAdd(&stats[c], ls[0] + ls[1] + ls[2] + ls[3]);
    atomicAdd(&stats[COUT + c], ls2[0] + ls2[1] + ls2[2] + ls2[3]);
  }
}

// ---------------- K5: normalize + scale/shift + ReLU ----------------
__global__ __launch_bounds__(256) void k_norm(const float* __restrict__ y,
                                              const float* __restrict__ stats,
                                              const float* __restrict__ gamma,
                                              const float* __restrict__ beta,
                                              float* __restrict__ out) {
  int i4 = blockIdx.x * 256 + threadIdx.x;
  const int total4 = BATCH * COUT * HW / 4;
  if (i4 >= total4) return;
  size_t i = (size_t)i4 * 4;
  int c = (int)((i / HW) & (COUT - 1));
  const float N = (float)(BATCH * HW);
  float m = stats[c] / N;
  float var = stats[COUT + c] / N - m * m;
  float r = rsqrtf(var + EPS);
  float g = gamma[c], bt = beta[c];
  float4 v = *(const float4*)&y[i];
  v.x = fmaxf(0.f, (v.x - m) * r * g + bt);
  v.y = fmaxf(0.f, (v.y - m) * r * g + bt);
  v.z = fmaxf(0.f, (v.z - m) * r * g + bt);
  v.w = fmaxf(0.f, (v.w - m) * r * g + bt);
  *(float4*)&out[i] = v;
}

extern "C" void kernel_launch(void* const* d_in, const int* in_sizes, int n_in,
                              void* d_out, int out_size, void* d_ws, size_t ws_size,
                              hipStream_t stream) {
  const float* x     = (const float*)d_in[0];
  const float* w_off = (const float*)d_in[1];
  const float* b_off = (const float*)d_in[2];
  const float* w_dcn = (const float*)d_in[3];
  // d_in[4] = b_dcn: cancels exactly through batch-norm
  const float* gamma = (const float*)d_in[5];
  const float* beta  = (const float*)d_in[6];
  float* out = (float*)d_out;

  float* ws = (float*)d_ws;
  float*  xT      = ws;                               // 6,422,528 floats
  float*  off_buf = xT + 6422528;                     // 1,806,336
  float*  w_r     = off_buf + 1806336;                //    10,368
  ushort* w_mf    = (ushort*)(w_r + 10368);           //    73,728 ushorts (36,864 floats)
  float*  y       = w_r + 10368 + 36864;              // 12,845,056
  float*  stats   = y + 12845056;                     //       256
  // total ~84.5 MB

  hipMemsetAsync(stats, 0, 256 * sizeof(float), stream);
  k_transpose_x<<<dim3(HW / 64, BATCH), 256, 0, stream>>>(x, xT);
  k_prep_w<<<(OFFC * KDIM + COUT * KDIM + 255) / 256, 256, 0, stream>>>(w_off, w_dcn, w_r, w_mf);
  k_offset_conv<<<dim3(HW / 256, BATCH), 256, 0, stream>>>(xT, w_r, b_off, off_buf);
  k_deform<<<dim3(HW / TP, BATCH), 256, 0, stream>>>(xT, off_buf, w_mf, y);
  k_stats<<<512, 256, 0, stream>>>(y, stats);
  k_norm<<<(BATCH * COUT * HW / 4 + 255) / 256, 256, 0, stream>>>(y, stats, gamma, beta, out);
}